// Round 7
// baseline (481.416 us; speedup 1.0000x reference)
//
#include <hip/hip_runtime.h>

// XSReLU percentile (B=1024 rows, N=65536 fp32), exact 80th percentile.
// One 256-thread block per row, 4 blocks/CU co-resident (cross-block overlap
// hides select phases). No register-resident row (that forced remat at 128
// VGPR); pass C re-reads the row from L2/L3.
//   pass A: stream row; reg-count below-band; direct-atomic gather of
//           [0.72,0.98) band (~4.7k cands for N(0,1)) into LDS.
//   select: fine 2048-bin histogram of cands + hierarchical wave scan +
//           tiny exact select (bit-identical to sort()[k]).
//   fallback (bracket miss; never taken for N(0,1)): exact 3-pass radix
//           histogram refinement over global re-reads.
//   pass C: re-read row (L2/L3-hot), write relu(v - cut).

#define TPB   256
#define BPT   8       // hist bins per thread = NB/TPB
#define NB    2048    // fine bins (fast) / max radix bins (fallback)
#define CAP   6144    // band candidate buffer; expected 4738 +- 66 (1 sigma)
#define TINY  64
#define BLO   0.72f
#define BHI   0.98f
#define NWAVE (TPB/64)

__device__ __forceinline__ unsigned f2ord(float f) {
    unsigned u = __float_as_uint(f);
    return (u & 0x80000000u) ? ~u : (u | 0x80000000u);
}
__device__ __forceinline__ float ord2f(unsigned u) {
    unsigned b = (u & 0x80000000u) ? (u ^ 0x80000000u) : ~u;
    return __uint_as_float(b);
}
__device__ __forceinline__ bool in_band(float f) { return f >= BLO && f < BHI; }

// All TPB threads participate. Finds bin b* with cum(hist[0..b*)) <= r < cum+hist[b*].
__device__ __forceinline__ void hist_select(const unsigned* hist, unsigned r, int tid,
                                            unsigned* wsum, unsigned* wbase,
                                            int* s_bin, unsigned* s_cum) {
    const int lane = tid & 63, wid = tid >> 6;
    const int b0 = tid * BPT;
    unsigned h[BPT];
    unsigned s = 0;
    #pragma unroll
    for (int j = 0; j < BPT; ++j) { h[j] = hist[b0 + j]; s += h[j]; }
    unsigned incl = s;                                      // wave inclusive scan
    #pragma unroll
    for (int off = 1; off < 64; off <<= 1) {
        unsigned t = __shfl_up(incl, off);
        if (lane >= off) incl += t;
    }
    if (lane == 63) wsum[wid] = incl;
    __syncthreads();
    if (tid == 0) {
        unsigned c = 0;
        #pragma unroll
        for (int w = 0; w < NWAVE; ++w) { wbase[w] = c; c += wsum[w]; }
    }
    __syncthreads();
    unsigned excl = wbase[wid] + incl - s;                  // global exclusive prefix
    if (r >= excl && r < excl + s) {                        // exactly one thread
        unsigned c = excl;
        #pragma unroll
        for (int j = 0; j < BPT; ++j) {
            if (r < c + h[j]) { *s_bin = b0 + j; *s_cum = c; break; }
            c += h[j];
        }
    }
    __syncthreads();
}

__global__ __launch_bounds__(TPB)
void xsrelu_fused(const float* __restrict__ in, float* __restrict__ out,
                  int N, int k) {
    const int row  = blockIdx.x;
    const int tid  = threadIdx.x;
    const int lane = tid & 63;
    const int nv   = N >> 2;
    const float SCALE = (float)NB / (BHI - BLO);
    const float4* __restrict__ rowv = (const float4*)(in + (size_t)row * (size_t)N);
    float4* __restrict__ outv = (float4*)(out + (size_t)row * (size_t)N);

    __shared__ unsigned hist[NB];
    __shared__ unsigned cand[CAP];
    __shared__ unsigned tiny[TINY];
    __shared__ unsigned wsum[NWAVE], wbase[NWAVE];
    __shared__ unsigned s_cnt, s_below, s_cum, s_tc;
    __shared__ int s_bin, s_fb;
    __shared__ float s_cut;

    for (int i = tid; i < NB; i += TPB) hist[i] = 0u;
    if (tid == 0) { s_cnt = 0u; s_below = 0u; s_tc = 0u; s_fb = 0; }
    __syncthreads();

    // ---- pass A: stream row; count below-band; gather band cands into LDS ----
    unsigned below = 0;
    for (int i = tid; i < nv; i += TPB) {
        float4 v = rowv[i];
        const float f[4] = {v.x, v.y, v.z, v.w};
        #pragma unroll
        for (int q = 0; q < 4; ++q) {
            below += (f[q] < BLO) ? 1u : 0u;
            if (in_band(f[q])) {                          // ~7% of lanes
                unsigned p = atomicAdd(&s_cnt, 1u);
                if (p < CAP) cand[p] = __float_as_uint(f[q]);  // positive: bits monotone
            }
        }
    }
    #pragma unroll
    for (int o = 32; o > 0; o >>= 1) below += __shfl_down(below, o);
    if (lane == 0) atomicAdd(&s_below, below);
    __syncthreads();

    const unsigned M0 = s_cnt;
    const long long r2ll = (long long)k - (long long)s_below;
    const bool fast = (M0 <= CAP) && (r2ll >= 0) && (r2ll < (long long)M0);

    if (fast) {
        const unsigned r2 = (unsigned)r2ll;
        // fine histogram from LDS candidates (~18 elems/thread, 2048 bins)
        for (unsigned i = tid; i < M0; i += TPB) {
            float f = __uint_as_float(cand[i]);
            int b = (int)((f - BLO) * SCALE);
            b = b < 0 ? 0 : (b >= NB ? NB - 1 : b);
            atomicAdd(&hist[b], 1u);
        }
        __syncthreads();
        hist_select(hist, r2, tid, wsum, wbase, &s_bin, &s_cum);
        const int bin = s_bin;
        const unsigned r3 = r2 - s_cum;
        for (unsigned i = tid; i < M0; i += TPB) {
            unsigned u = cand[i];
            float f = __uint_as_float(u);
            int b = (int)((f - BLO) * SCALE);
            b = b < 0 ? 0 : (b >= NB ? NB - 1 : b);
            if (b == bin) { unsigned pp = atomicAdd(&s_tc, 1u); if (pp < TINY) tiny[pp] = u; }
        }
        __syncthreads();
        const unsigned c = s_tc;
        if (c > TINY) { if (tid == 0) s_fb = 1; }
        else if (tid < 64) {
            unsigned uj = (lane < (int)c) ? tiny[lane] : 0xFFFFFFFFu;
            unsigned less = 0, eq = 0;
            for (unsigned i2 = 0; i2 < c; ++i2) {
                unsigned ui = tiny[i2];
                less += (ui < uj) ? 1u : 0u;
                eq   += (ui == uj) ? 1u : 0u;
            }
            bool cond = (lane < (int)c) && (less <= r3) && (r3 < less + eq);
            unsigned long long cm = __ballot(cond);
            if (cond && lane == __ffsll((long long)cm) - 1)
                s_cut = __uint_as_float(uj);
        }
    } else {
        if (tid == 0) s_fb = 1;
    }
    __syncthreads();

    if (s_fb) {
        // ---- exact fallback: 3-pass radix refinement over global re-reads ----
        unsigned prefix = 0;
        unsigned rr = (unsigned)k;
        const int shifts[3] = {21, 10, 0};
        const int bitsc[3]  = {11, 11, 10};
        for (int pass = 0; pass < 3; ++pass) {
            const int sh = shifts[pass];
            const unsigned nbm = (1u << bitsc[pass]) - 1u;
            for (int i = tid; i < NB; i += TPB) hist[i] = 0u;
            __syncthreads();
            for (int i = tid; i < nv; i += TPB) {
                float4 v = rowv[i];
                const float f[4] = {v.x, v.y, v.z, v.w};
                #pragma unroll
                for (int q = 0; q < 4; ++q) {
                    unsigned u = f2ord(f[q]);
                    if (pass == 0 || (u >> (sh + bitsc[pass])) == prefix)
                        atomicAdd(&hist[(u >> sh) & nbm], 1u);
                }
            }
            __syncthreads();
            hist_select(hist, rr, tid, wsum, wbase, &s_bin, &s_cum);
            prefix = (prefix << bitsc[pass]) | (unsigned)s_bin;
            rr -= s_cum;
        }
        if (tid == 0) s_cut = ord2f(prefix);
        __syncthreads();
    }

    const float cut = s_cut;

    // ---- pass C: re-read row (L2/L3-hot) and write relu(v - cut) ----
    for (int i = tid; i < nv; i += TPB) {
        float4 v = rowv[i];
        float4 o;
        o.x = fmaxf(v.x - cut, 0.0f);
        o.y = fmaxf(v.y - cut, 0.0f);
        o.z = fmaxf(v.z - cut, 0.0f);
        o.w = fmaxf(v.w - cut, 0.0f);
        outv[i] = o;
    }
}

extern "C" void kernel_launch(void* const* d_in, const int* in_sizes, int n_in,
                              void* d_out, int out_size, void* d_ws, size_t ws_size,
                              hipStream_t stream) {
    const float* in = (const float*)d_in[0];
    float* out = (float*)d_out;
    const int N = 65536;
    const int B = in_sizes[0] / N;                        // 1024
    const int k = (int)(((long long)N * 4) / 5);          // 52428

    xsrelu_fused<<<dim3(B), dim3(TPB), 0, stream>>>(in, out, N, k);
}